// Round 9
// baseline (4948.825 us; speedup 1.0000x reference)
//
#include <hip/hip_runtime.h>
#include <hip/hip_bf16.h>

static constexpr int T_ = 512, B_ = 128, DIM_ = 512, H_ = 1024, OUT_ = 512;
static constexpr size_t BH = (size_t)B_ * H_;
static constexpr size_t HH = (size_t)H_ * H_;

using short8 = __attribute__((ext_vector_type(8))) short;
using f32x4  = __attribute__((ext_vector_type(4))) float;

// ---- bf16 bit helpers (round-to-nearest-even) ----
__device__ __forceinline__ unsigned short f32_to_bf16(float x) {
    unsigned int u = __float_as_uint(x);
    u += 0x7fffu + ((u >> 16) & 1u);
    return (unsigned short)(u >> 16);
}
__device__ __forceinline__ float bf16_to_f32(unsigned short h) {
    return __uint_as_float(((unsigned int)h) << 16);
}

__global__ void copy_h0_kernel(const float* __restrict__ h0, float* __restrict__ out) {
    int i = blockIdx.x * blockDim.x + threadIdx.x;
    if (i < B_ * H_) out[i] = h0[i];
}

// f32 -> separate bf16 hi/lo planes (for Wh and the v4 fallback)
__global__ void cvt_planes_kernel(const float* __restrict__ src,
                                  unsigned short* __restrict__ hi,
                                  unsigned short* __restrict__ lo, int n4)
{
    int i = blockIdx.x * blockDim.x + threadIdx.x;
    if (i >= n4) return;
    const float4 v = *(const float4*)(src + (size_t)i * 4);
    unsigned short h[4] = {f32_to_bf16(v.x), f32_to_bf16(v.y),
                           f32_to_bf16(v.z), f32_to_bf16(v.w)};
    unsigned short l[4] = {f32_to_bf16(v.x - bf16_to_f32(h[0])),
                           f32_to_bf16(v.y - bf16_to_f32(h[1])),
                           f32_to_bf16(v.z - bf16_to_f32(h[2])),
                           f32_to_bf16(v.w - bf16_to_f32(h[3]))};
    *(ushort4*)(hi + (size_t)i * 4) = make_ushort4(h[0], h[1], h[2], h[3]);
    *(ushort4*)(lo + (size_t)i * 4) = make_ushort4(l[0], l[1], l[2], l[3]);
}

// f32 -> packed (hi | lo<<16) u32 plane (persistent-kernel h state)
__global__ void pack_plane_kernel(const float* __restrict__ src,
                                  unsigned int* __restrict__ q, int n)
{
    int i = blockIdx.x * blockDim.x + threadIdx.x;
    if (i >= n) return;
    const float v = src[i];
    const unsigned short hi = f32_to_bf16(v);
    const unsigned short lo = f32_to_bf16(v - bf16_to_f32(hi));
    q[i] = (unsigned int)hi | ((unsigned int)lo << 16);
}

// ================= MFMA GEMM (unchanged from round 7) =================
template<int SPLIT, int NB, int ACT>
__launch_bounds__(256)
__global__ void mfma_gemm(const float* __restrict__ A, const float* __restrict__ W,
                          const float* __restrict__ b1, const float* __restrict__ b2,
                          float* __restrict__ outp, int M, int N, int K)
{
    __shared__ unsigned short Ahi[128 * 32], Alo[SPLIT ? 128 * 32 : 1];
    __shared__ unsigned short Bhi[128 * 32], Blo[SPLIT ? 128 * 32 : 1];

    const int tid  = threadIdx.x;
    const int col0 = blockIdx.x * 128;
    const int row0 = blockIdx.y * 128;

    const int wv   = tid >> 6;
    const int lane = tid & 63;
    const int wr   = (wv >> 1) * 64;
    const int wc   = (wv & 1) * 64;

    f32x4 acc[4][4];
    #pragma unroll
    for (int i = 0; i < 4; ++i)
        #pragma unroll
        for (int j = 0; j < 4; ++j) acc[i][j] = (f32x4){0.f, 0.f, 0.f, 0.f};

    auto frag_off = [](int row, int unit) -> int {
        return row * 32 + ((unit ^ ((row >> 1) & 3)) << 3);
    };

    for (int k0 = 0; k0 < K; k0 += 32) {
        __syncthreads();
        #pragma unroll
        for (int i = 0; i < 4; ++i) {
            const int fid = tid + i * 256;
            const int row = fid >> 3;
            const int f4  = fid & 7;
            const int unit = f4 >> 1;
            const int uoff = ((unit ^ ((row >> 1) & 3)) << 3) + (f4 & 1) * 4;

            float4 av = *(const float4*)(A + (size_t)(row0 + row) * K + k0 + f4 * 4);
            float4 wvv = *(const float4*)(W + (size_t)(col0 + row) * K + k0 + f4 * 4);

            unsigned short ah[4] = {f32_to_bf16(av.x), f32_to_bf16(av.y),
                                    f32_to_bf16(av.z), f32_to_bf16(av.w)};
            unsigned short bh[4] = {f32_to_bf16(wvv.x), f32_to_bf16(wvv.y),
                                    f32_to_bf16(wvv.z), f32_to_bf16(wvv.w)};
            *(ushort4*)&Ahi[row * 32 + uoff] = make_ushort4(ah[0], ah[1], ah[2], ah[3]);
            *(ushort4*)&Bhi[row * 32 + uoff] = make_ushort4(bh[0], bh[1], bh[2], bh[3]);

            if constexpr (SPLIT) {
                unsigned short al[4] = {
                    f32_to_bf16(av.x - bf16_to_f32(ah[0])),
                    f32_to_bf16(av.y - bf16_to_f32(ah[1])),
                    f32_to_bf16(av.z - bf16_to_f32(ah[2])),
                    f32_to_bf16(av.w - bf16_to_f32(ah[3]))};
                unsigned short bl[4] = {
                    f32_to_bf16(wvv.x - bf16_to_f32(bh[0])),
                    f32_to_bf16(wvv.y - bf16_to_f32(bh[1])),
                    f32_to_bf16(wvv.z - bf16_to_f32(bh[2])),
                    f32_to_bf16(wvv.w - bf16_to_f32(bh[3]))};
                *(ushort4*)&Alo[row * 32 + uoff] = make_ushort4(al[0], al[1], al[2], al[3]);
                *(ushort4*)&Blo[row * 32 + uoff] = make_ushort4(bl[0], bl[1], bl[2], bl[3]);
            }
        }
        __syncthreads();

        const int lrow = lane & 15;
        const int unit = lane >> 4;

        short8 bh_f[4], bl_f[4];
        #pragma unroll
        for (int fc = 0; fc < 4; ++fc) {
            bh_f[fc] = *(const short8*)&Bhi[frag_off(wc + fc * 16 + lrow, unit)];
            if constexpr (SPLIT)
                bl_f[fc] = *(const short8*)&Blo[frag_off(wc + fc * 16 + lrow, unit)];
        }
        #pragma unroll
        for (int fr = 0; fr < 4; ++fr) {
            const short8 ah_f = *(const short8*)&Ahi[frag_off(wr + fr * 16 + lrow, unit)];
            if constexpr (SPLIT) {
                const short8 al_f = *(const short8*)&Alo[frag_off(wr + fr * 16 + lrow, unit)];
                #pragma unroll
                for (int fc = 0; fc < 4; ++fc) {
                    acc[fr][fc] = __builtin_amdgcn_mfma_f32_16x16x32_bf16(ah_f, bh_f[fc], acc[fr][fc], 0, 0, 0);
                    acc[fr][fc] = __builtin_amdgcn_mfma_f32_16x16x32_bf16(ah_f, bl_f[fc], acc[fr][fc], 0, 0, 0);
                    acc[fr][fc] = __builtin_amdgcn_mfma_f32_16x16x32_bf16(al_f, bh_f[fc], acc[fr][fc], 0, 0, 0);
                }
            } else {
                #pragma unroll
                for (int fc = 0; fc < 4; ++fc)
                    acc[fr][fc] = __builtin_amdgcn_mfma_f32_16x16x32_bf16(ah_f, bh_f[fc], acc[fr][fc], 0, 0, 0);
            }
        }
    }

    const int ccol = lane & 15;
    const int crow = (lane >> 4) * 4;
    #pragma unroll
    for (int fr = 0; fr < 4; ++fr) {
        #pragma unroll
        for (int fc = 0; fc < 4; ++fc) {
            const int col = col0 + wc + fc * 16 + ccol;
            float bias = 0.f;
            if constexpr (NB >= 1) bias += b1[col];
            if constexpr (NB >= 2) bias += b2[col];
            #pragma unroll
            for (int j = 0; j < 4; ++j) {
                const int row = row0 + wr + fr * 16 + crow + j;
                float v = acc[fr][fc][j] + bias;
                if constexpr (ACT == 1) v = tanhf(v);
                else if constexpr (ACT == 2) v = 1.0f / (1.0f + expf(-v));
                outp[(size_t)row * N + col] = v;
            }
        }
    }
}

// ============ persistent recurrence: all 512 steps, one launch ============
// Row-groups are independent recurrences: h_{t+1}[r] needs only h_t[r].
// 256 blocks x 512 thr; y = bid>>5 (row-group, 16 rows), x = bid&31 (32 cols).
// Only intra-group (32 blocks) column exchange per step. Sync: per-group
// counter via FENCE-FREE relaxed agent-scope atomic RMWs (execute at the
// coherence point -> correct for any block->XCD mapping; no L2 writebacks).
// h state: packed (bf16hi | bf16lo<<16) u32 planes, exchanged with explicit
// sc0 sc1 loads/stores (bypass non-coherent L2s, live in L3). Wh hi/lo planes
// are read-only and L2-cached normally. Numerics identical to step_v4.
__global__ __launch_bounds__(512, 1)
void rnn_persistent(const unsigned int* __restrict__ Ppk,  // [2][B][H] packed
                    const unsigned short* __restrict__ Whi,
                    const unsigned short* __restrict__ Wlo,
                    float* __restrict__ all_h,
                    unsigned int* __restrict__ ctr)        // [8][T_]
{
    __shared__ float red[8][16][33];

    const int tid  = threadIdx.x;
    const int bid  = blockIdx.x;
    const int y    = bid >> 5;          // row-group 0..7
    const int x    = bid & 31;          // col-block 0..31 (XCD = bid%8 spreads x)
    const int r0   = y * 16;
    const int c0   = x * 32;

    const int w    = tid >> 6;          // wave: k-range [w*128, +128)
    const int lane = tid & 63;
    const int lr   = lane & 15;
    const int kg   = lane >> 4;

    const int ep_r = tid >> 5, ep_c = tid & 31;
    const size_t ep_idx = (size_t)(r0 + ep_r) * H_ + (c0 + ep_c);

    const unsigned short* pb0h = Whi + (size_t)(c0 + lr) * H_ + w * 128 + kg * 8;
    const unsigned short* pb0l = Wlo + (size_t)(c0 + lr) * H_ + w * 128 + kg * 8;
    const unsigned short* pb1h = Whi + (size_t)(c0 + 16 + lr) * H_ + w * 128 + kg * 8;
    const unsigned short* pb1l = Wlo + (size_t)(c0 + 16 + lr) * H_ + w * 128 + kg * 8;

    unsigned int* ctr_y = ctr + (size_t)y * T_;

    for (int t = 0; t < T_; ++t) {
        float* __restrict__ hdst = all_h + (size_t)(t + 1) * BH;
        const float xpv = hdst[ep_idx];          // staged xp (clean lines)

        // ---- A: packed h_t, 8x dwordx4 sc0 sc1 in one asm block ----
        const unsigned int* abase = Ppk + (size_t)(t & 1) * BH
                                  + (size_t)(r0 + lr) * H_ + w * 128 + kg * 8;
        uint4 c0v, c1v, c2v, c3v, c4v, c5v, c6v, c7v;
        asm volatile(
            "global_load_dwordx4 %0, %8, off sc0 sc1\n\t"
            "global_load_dwordx4 %1, %8, off offset:16 sc0 sc1\n\t"
            "global_load_dwordx4 %2, %8, off offset:128 sc0 sc1\n\t"
            "global_load_dwordx4 %3, %8, off offset:144 sc0 sc1\n\t"
            "global_load_dwordx4 %4, %8, off offset:256 sc0 sc1\n\t"
            "global_load_dwordx4 %5, %8, off offset:272 sc0 sc1\n\t"
            "global_load_dwordx4 %6, %8, off offset:384 sc0 sc1\n\t"
            "global_load_dwordx4 %7, %8, off offset:400 sc0 sc1\n\t"
            "s_waitcnt vmcnt(0)"
            : "=&v"(c0v), "=&v"(c1v), "=&v"(c2v), "=&v"(c3v),
              "=&v"(c4v), "=&v"(c5v), "=&v"(c6v), "=&v"(c7v)
            : "v"(abase)
            : "memory");

        f32x4 acc0 = {0.f, 0.f, 0.f, 0.f}, acc1 = {0.f, 0.f, 0.f, 0.f};
        const uint4 chunks[8] = {c0v, c1v, c2v, c3v, c4v, c5v, c6v, c7v};

        #pragma unroll
        for (int it = 0; it < 4; ++it) {
            // unpack packed u32 -> hi/lo short8
            short8 ah, al;
            #pragma unroll
            for (int j = 0; j < 4; ++j) {
                const unsigned int u0 = ((const unsigned int*)&chunks[2 * it])[j];
                const unsigned int u1 = ((const unsigned int*)&chunks[2 * it + 1])[j];
                ah[j]     = (short)(u0 & 0xffffu);
                al[j]     = (short)(u0 >> 16);
                ah[4 + j] = (short)(u1 & 0xffffu);
                al[4 + j] = (short)(u1 >> 16);
            }
            const int ko = it * 32;
            const short8 b0h = *(const short8*)(pb0h + ko);
            const short8 b0l = *(const short8*)(pb0l + ko);
            const short8 b1h = *(const short8*)(pb1h + ko);
            const short8 b1l = *(const short8*)(pb1l + ko);

            acc0 = __builtin_amdgcn_mfma_f32_16x16x32_bf16(ah, b0h, acc0, 0, 0, 0);
            acc0 = __builtin_amdgcn_mfma_f32_16x16x32_bf16(ah, b0l, acc0, 0, 0, 0);
            acc0 = __builtin_amdgcn_mfma_f32_16x16x32_bf16(al, b0h, acc0, 0, 0, 0);
            acc0 = __builtin_amdgcn_mfma_f32_16x16x32_bf16(al, b0l, acc0, 0, 0, 0);
            acc1 = __builtin_amdgcn_mfma_f32_16x16x32_bf16(ah, b1h, acc1, 0, 0, 0);
            acc1 = __builtin_amdgcn_mfma_f32_16x16x32_bf16(ah, b1l, acc1, 0, 0, 0);
            acc1 = __builtin_amdgcn_mfma_f32_16x16x32_bf16(al, b1h, acc1, 0, 0, 0);
            acc1 = __builtin_amdgcn_mfma_f32_16x16x32_bf16(al, b1l, acc1, 0, 0, 0);
        }

        #pragma unroll
        for (int j = 0; j < 4; ++j) {
            red[w][kg * 4 + j][lr]      = acc0[j];
            red[w][kg * 4 + j][16 + lr] = acc1[j];
        }
        __syncthreads();

        // epilogue: one cell/thread
        {
            float s = ((red[0][ep_r][ep_c] + red[1][ep_r][ep_c])
                     + (red[2][ep_r][ep_c] + red[3][ep_r][ep_c]))
                    + ((red[4][ep_r][ep_c] + red[5][ep_r][ep_c])
                     + (red[6][ep_r][ep_c] + red[7][ep_r][ep_c]));
            const float v = tanhf(s + xpv);
            hdst[ep_idx] = v;                    // plain store (output only)
            const unsigned short hi = f32_to_bf16(v);
            const unsigned short lo = f32_to_bf16(v - bf16_to_f32(hi));
            const unsigned int pk = (unsigned int)hi | ((unsigned int)lo << 16);
            const unsigned int* qp = Ppk + (size_t)((t + 1) & 1) * BH + ep_idx;
            asm volatile("global_store_dword %0, %1, off sc0 sc1"
                         :: "v"(qp), "v"(pk) : "memory");
        }

        // ---- intra-group barrier: fence-free, coherence-point atomics ----
        asm volatile("s_waitcnt vmcnt(0)" ::: "memory");
        __syncthreads();
        if (tid == 0) {
            __hip_atomic_fetch_add(&ctr_y[t], 1u, __ATOMIC_RELAXED,
                                   __HIP_MEMORY_SCOPE_AGENT);
            int spins = 0;
            while (__hip_atomic_fetch_add(&ctr_y[t], 0u, __ATOMIC_RELAXED,
                                          __HIP_MEMORY_SCOPE_AGENT) < 32u) {
                __builtin_amdgcn_s_sleep(4);
                if (++spins > (1 << 15)) break;   // fail-wrong-fast, never hang
            }
        }
        __syncthreads();
    }
}

// ---------------- step_v4 fallback (round 8) ----------------
__global__ __launch_bounds__(512)
void step_v4(const unsigned short* __restrict__ Phi, const unsigned short* __restrict__ Plo,
             const unsigned short* __restrict__ Whi, const unsigned short* __restrict__ Wlo,
             float* __restrict__ hdst,
             unsigned short* __restrict__ Qhi, unsigned short* __restrict__ Qlo)
{
    __shared__ float red[8][16][33];

    const int tid  = threadIdx.x;
    const int c0   = blockIdx.x * 32;
    const int r0   = blockIdx.y * 16;
    const int w    = tid >> 6;
    const int lane = tid & 63;
    const int lr   = lane & 15;
    const int kg   = lane >> 4;

    const int ep_r = tid >> 5, ep_c = tid & 31;
    const size_t ep_idx = (size_t)(r0 + ep_r) * H_ + (c0 + ep_c);
    const float xpv = hdst[ep_idx];

    const int kbase = w * 128 + kg * 8;
    const unsigned short* pah = Phi + (size_t)(r0 + lr) * H_ + kbase;
    const unsigned short* pal = Plo + (size_t)(r0 + lr) * H_ + kbase;
    const unsigned short* pb0h = Whi + (size_t)(c0 + lr) * H_ + kbase;
    const unsigned short* pb0l = Wlo + (size_t)(c0 + lr) * H_ + kbase;
    const unsigned short* pb1h = Whi + (size_t)(c0 + 16 + lr) * H_ + kbase;
    const unsigned short* pb1l = Wlo + (size_t)(c0 + 16 + lr) * H_ + kbase;

    f32x4 acc0 = {0.f, 0.f, 0.f, 0.f}, acc1 = {0.f, 0.f, 0.f, 0.f};

    #pragma unroll
    for (int it = 0; it < 4; ++it) {
        const int ko = it * 32;
        const short8 ah  = *(const short8*)(pah + ko);
        const short8 al  = *(const short8*)(pal + ko);
        const short8 b0h = *(const short8*)(pb0h + ko);
        const short8 b0l = *(const short8*)(pb0l + ko);
        const short8 b1h = *(const short8*)(pb1h + ko);
        const short8 b1l = *(const short8*)(pb1l + ko);

        acc0 = __builtin_amdgcn_mfma_f32_16x16x32_bf16(ah, b0h, acc0, 0, 0, 0);
        acc0 = __builtin_amdgcn_mfma_f32_16x16x32_bf16(ah, b0l, acc0, 0, 0, 0);
        acc0 = __builtin_amdgcn_mfma_f32_16x16x32_bf16(al, b0h, acc0, 0, 0, 0);
        acc0 = __builtin_amdgcn_mfma_f32_16x16x32_bf16(al, b0l, acc0, 0, 0, 0);
        acc1 = __builtin_amdgcn_mfma_f32_16x16x32_bf16(ah, b1h, acc1, 0, 0, 0);
        acc1 = __builtin_amdgcn_mfma_f32_16x16x32_bf16(ah, b1l, acc1, 0, 0, 0);
        acc1 = __builtin_amdgcn_mfma_f32_16x16x32_bf16(al, b1h, acc1, 0, 0, 0);
        acc1 = __builtin_amdgcn_mfma_f32_16x16x32_bf16(al, b1l, acc1, 0, 0, 0);
    }

    #pragma unroll
    for (int j = 0; j < 4; ++j) {
        red[w][kg * 4 + j][lr]      = acc0[j];
        red[w][kg * 4 + j][16 + lr] = acc1[j];
    }
    __syncthreads();

    float s = ((red[0][ep_r][ep_c] + red[1][ep_r][ep_c])
             + (red[2][ep_r][ep_c] + red[3][ep_r][ep_c]))
            + ((red[4][ep_r][ep_c] + red[5][ep_r][ep_c])
             + (red[6][ep_r][ep_c] + red[7][ep_r][ep_c]));
    const float v = tanhf(s + xpv);
    hdst[ep_idx] = v;
    const unsigned short hi = f32_to_bf16(v);
    Qhi[ep_idx] = hi;
    Qlo[ep_idx] = f32_to_bf16(v - bf16_to_f32(hi));
}

// ---------------- step_v3 fallback (round 6) ----------------
__global__ __launch_bounds__(512)
void step_v3(const float* __restrict__ hsrc, const float* __restrict__ Wh,
             float* __restrict__ hdst)
{
    __shared__ float hS[16][1024];
    __shared__ float red[16][33];

    const int tid = threadIdx.x;
    const int c0  = blockIdx.x * 32;
    const int r0  = blockIdx.y * 16;

    const int ep_r = tid >> 5, ep_c = tid & 31;
    const size_t ep_idx = (size_t)(r0 + ep_r) * H_ + (c0 + ep_c);
    const float xpv = hdst[ep_idx];

    #pragma unroll
    for (int it = 0; it < 8; ++it) {
        const int chunk = tid + it * 512;
        const int row = chunk >> 8;
        const int k4  = (chunk & 255) * 4;
        *(float4*)&hS[row][k4] =
            *(const float4*)(hsrc + (size_t)(r0 + row) * H_ + k4);
    }
    __syncthreads();

    const int w     = tid >> 6;
    const int lane  = tid & 63;
    const int kslot = lane & 15;
    const int rq    = lane >> 4;

    float acc[4][4];
    #pragma unroll
    for (int r = 0; r < 4; ++r)
        #pragma unroll
        for (int c = 0; c < 4; ++c) acc[r][c] = 0.f;

    const float* whb = Wh + (size_t)(c0 + w * 4) * H_ + kslot * 4;

    #pragma unroll 4
    for (int i = 0; i < 16; ++i) {
        const int k = kslot * 4 + i * 64;
        float4 hv[4];
        #pragma unroll
        for (int r = 0; r < 4; ++r)
            hv[r] = *(const float4*)&hS[rq * 4 + r][k];
        #pragma unroll
        for (int c = 0; c < 4; ++c) {
            const float4 wvv = *(const float4*)(whb + (size_t)c * H_ + i * 64);
            #pragma unroll
            for (int r = 0; r < 4; ++r) {
                acc[r][c] = fmaf(hv[r].x, wvv.x, acc[r][c]);
                acc[r][c] = fmaf(hv[r].y, wvv.y, acc[r][c]);
                acc[r][c] = fmaf(hv[r].z, wvv.z, acc[r][c]);
                acc[r][c] = fmaf(hv[r].w, wvv.w, acc[r][c]);
            }
        }
    }

    #pragma unroll
    for (int m = 1; m < 16; m <<= 1)
        #pragma unroll
        for (int r = 0; r < 4; ++r)
            #pragma unroll
            for (int c = 0; c < 4; ++c)
                acc[r][c] += __shfl_xor(acc[r][c], m, 64);

    if (kslot == 0) {
        #pragma unroll
        for (int r = 0; r < 4; ++r)
            #pragma unroll
            for (int c = 0; c < 4; ++c)
                red[rq * 4 + r][w * 4 + c] = acc[r][c];
    }
    __syncthreads();

    hdst[ep_idx] = tanhf(red[ep_r][ep_c] + xpv);
}

extern "C" void kernel_launch(void* const* d_in, const int* in_sizes, int n_in,
                              void* d_out, int out_size, void* d_ws, size_t ws_size,
                              hipStream_t stream)
{
    const float* x    = (const float*)d_in[0];
    const float* h0   = (const float*)d_in[1];
    const float* Wx_w = (const float*)d_in[2];
    const float* Wx_b = (const float*)d_in[3];
    const float* Wh_w = (const float*)d_in[4];
    const float* Wh_b = (const float*)d_in[5];
    const float* Wo_w = (const float*)d_in[6];
    const float* Wo_b = (const float*)d_in[7];

    float* out   = (float*)d_out;
    float* all_h = out;                              // [T+1][B][H]
    float* all_y = out + (size_t)(T_ + 1) * BH;      // [T][B][OUT]
    float* last  = all_y + (size_t)T_ * B_ * OUT_;   // [B][OUT]

    // all_h[0] = h0
    copy_h0_kernel<<<dim3((B_*H_ + 255)/256), dim3(256), 0, stream>>>(h0, all_h);

    // xproj = x@Wx^T + Wx_b + Wh_b (bf16x3 MFMA) -> staged into all_h[1..T]
    mfma_gemm<1, 2, 0><<<dim3(H_/128, (T_*B_)/128), dim3(256), 0, stream>>>(
        x, Wx_w, Wx_b, Wh_b, all_h + BH, T_*B_, H_, DIM_);

    // ---- recurrence ----
    const size_t need_pers = 2 * HH * sizeof(unsigned short)
                           + (2 * BH + 8 * (size_t)T_) * sizeof(unsigned int);
    const size_t need_v4   = (2 * HH + 4 * BH) * sizeof(unsigned short);

    if (ws_size >= need_pers) {
        unsigned short* Whi = (unsigned short*)d_ws;
        unsigned short* Wlo = Whi + HH;
        unsigned int*   Ppk = (unsigned int*)(Whi + 2 * HH);   // [2][B][H]
        unsigned int*   ctr = Ppk + 2 * BH;                    // [8][T_]

        cvt_planes_kernel<<<dim3((int)(HH/4/256)), dim3(256), 0, stream>>>(
            Wh_w, Whi, Wlo, (int)(HH/4));
        pack_plane_kernel<<<dim3((int)(BH/256)), dim3(256), 0, stream>>>(
            h0, Ppk, (int)BH);
        hipMemsetAsync(ctr, 0, 8 * (size_t)T_ * sizeof(unsigned int), stream);

        rnn_persistent<<<dim3(256), dim3(512), 0, stream>>>(
            Ppk, Whi, Wlo, all_h, ctr);
    } else if (ws_size >= need_v4) {
        unsigned short* wsu = (unsigned short*)d_ws;
        unsigned short* Whi = wsu;
        unsigned short* Wlo = wsu + HH;
        unsigned short* P0h = wsu + 2 * HH;
        unsigned short* P0l = P0h + BH;
        unsigned short* P1h = P0l + BH;
        unsigned short* P1l = P1h + BH;

        cvt_planes_kernel<<<dim3((int)(HH/4/256)), dim3(256), 0, stream>>>(
            Wh_w, Whi, Wlo, (int)(HH/4));
        cvt_planes_kernel<<<dim3((int)(BH/4/256)), dim3(256), 0, stream>>>(
            h0, P0h, P0l, (int)(BH/4));

        for (int t = 0; t < T_; ++t) {
            unsigned short* ph = (t & 1) ? P1h : P0h;
            unsigned short* pl = (t & 1) ? P1l : P0l;
            unsigned short* qh = (t & 1) ? P0h : P1h;
            unsigned short* ql = (t & 1) ? P0l : P1l;
            step_v4<<<dim3(32, 8), dim3(512), 0, stream>>>(
                ph, pl, Whi, Wlo, all_h + (size_t)(t + 1) * BH, qh, ql);
        }
    } else {
        for (int t = 0; t < T_; ++t) {
            step_v3<<<dim3(32, 8), dim3(512), 0, stream>>>(
                all_h + (size_t)t * BH, Wh_w, all_h + (size_t)(t + 1) * BH);
        }
    }

    // all_y = sigmoid(hs @ Wo^T + Wo_b)  (plain bf16 MFMA — downstream of scan)
    mfma_gemm<0, 1, 2><<<dim3(OUT_/128, (T_*B_)/128), dim3(256), 0, stream>>>(
        all_h + BH, Wo_w, Wo_b, nullptr, all_y, T_*B_, OUT_, H_);

    // last_logits = h_T @ Wo^T + Wo_b
    mfma_gemm<0, 1, 0><<<dim3(OUT_/128, 1), dim3(256), 0, stream>>>(
        all_h + (size_t)T_ * BH, Wo_w, Wo_b, nullptr, last, B_, OUT_, H_);
}

// Round 10
// 3134.564 us; speedup vs baseline: 1.5788x; 1.5788x over previous
//
#include <hip/hip_runtime.h>
#include <hip/hip_bf16.h>

static constexpr int T_ = 512, B_ = 128, DIM_ = 512, H_ = 1024, OUT_ = 512;
static constexpr size_t BH = (size_t)B_ * H_;
static constexpr size_t HH = (size_t)H_ * H_;

using short8 = __attribute__((ext_vector_type(8))) short;
using f32x4  = __attribute__((ext_vector_type(4))) float;

// ---- bf16 bit helpers (round-to-nearest-even) ----
__device__ __forceinline__ unsigned short f32_to_bf16(float x) {
    unsigned int u = __float_as_uint(x);
    u += 0x7fffu + ((u >> 16) & 1u);
    return (unsigned short)(u >> 16);
}
__device__ __forceinline__ float bf16_to_f32(unsigned short h) {
    return __uint_as_float(((unsigned int)h) << 16);
}

__global__ void copy_h0_kernel(const float* __restrict__ h0, float* __restrict__ out) {
    int i = blockIdx.x * blockDim.x + threadIdx.x;
    if (i < B_ * H_) out[i] = h0[i];
}

// f32 -> separate bf16 hi/lo planes (for Wh and the v4 fallback)
__global__ void cvt_planes_kernel(const float* __restrict__ src,
                                  unsigned short* __restrict__ hi,
                                  unsigned short* __restrict__ lo, int n4)
{
    int i = blockIdx.x * blockDim.x + threadIdx.x;
    if (i >= n4) return;
    const float4 v = *(const float4*)(src + (size_t)i * 4);
    unsigned short h[4] = {f32_to_bf16(v.x), f32_to_bf16(v.y),
                           f32_to_bf16(v.z), f32_to_bf16(v.w)};
    unsigned short l[4] = {f32_to_bf16(v.x - bf16_to_f32(h[0])),
                           f32_to_bf16(v.y - bf16_to_f32(h[1])),
                           f32_to_bf16(v.z - bf16_to_f32(h[2])),
                           f32_to_bf16(v.w - bf16_to_f32(h[3]))};
    *(ushort4*)(hi + (size_t)i * 4) = make_ushort4(h[0], h[1], h[2], h[3]);
    *(ushort4*)(lo + (size_t)i * 4) = make_ushort4(l[0], l[1], l[2], l[3]);
}

// f32 -> packed (hi | lo<<16) u32 plane (persistent-kernel h state)
__global__ void pack_plane_kernel(const float* __restrict__ src,
                                  unsigned int* __restrict__ q, int n)
{
    int i = blockIdx.x * blockDim.x + threadIdx.x;
    if (i >= n) return;
    const float v = src[i];
    const unsigned short hi = f32_to_bf16(v);
    const unsigned short lo = f32_to_bf16(v - bf16_to_f32(hi));
    q[i] = (unsigned int)hi | ((unsigned int)lo << 16);
}

// ================= MFMA GEMM (unchanged from round 7) =================
template<int SPLIT, int NB, int ACT>
__launch_bounds__(256)
__global__ void mfma_gemm(const float* __restrict__ A, const float* __restrict__ W,
                          const float* __restrict__ b1, const float* __restrict__ b2,
                          float* __restrict__ outp, int M, int N, int K)
{
    __shared__ unsigned short Ahi[128 * 32], Alo[SPLIT ? 128 * 32 : 1];
    __shared__ unsigned short Bhi[128 * 32], Blo[SPLIT ? 128 * 32 : 1];

    const int tid  = threadIdx.x;
    const int col0 = blockIdx.x * 128;
    const int row0 = blockIdx.y * 128;

    const int wv   = tid >> 6;
    const int lane = tid & 63;
    const int wr   = (wv >> 1) * 64;
    const int wc   = (wv & 1) * 64;

    f32x4 acc[4][4];
    #pragma unroll
    for (int i = 0; i < 4; ++i)
        #pragma unroll
        for (int j = 0; j < 4; ++j) acc[i][j] = (f32x4){0.f, 0.f, 0.f, 0.f};

    auto frag_off = [](int row, int unit) -> int {
        return row * 32 + ((unit ^ ((row >> 1) & 3)) << 3);
    };

    for (int k0 = 0; k0 < K; k0 += 32) {
        __syncthreads();
        #pragma unroll
        for (int i = 0; i < 4; ++i) {
            const int fid = tid + i * 256;
            const int row = fid >> 3;
            const int f4  = fid & 7;
            const int unit = f4 >> 1;
            const int uoff = ((unit ^ ((row >> 1) & 3)) << 3) + (f4 & 1) * 4;

            float4 av = *(const float4*)(A + (size_t)(row0 + row) * K + k0 + f4 * 4);
            float4 wvv = *(const float4*)(W + (size_t)(col0 + row) * K + k0 + f4 * 4);

            unsigned short ah[4] = {f32_to_bf16(av.x), f32_to_bf16(av.y),
                                    f32_to_bf16(av.z), f32_to_bf16(av.w)};
            unsigned short bh[4] = {f32_to_bf16(wvv.x), f32_to_bf16(wvv.y),
                                    f32_to_bf16(wvv.z), f32_to_bf16(wvv.w)};
            *(ushort4*)&Ahi[row * 32 + uoff] = make_ushort4(ah[0], ah[1], ah[2], ah[3]);
            *(ushort4*)&Bhi[row * 32 + uoff] = make_ushort4(bh[0], bh[1], bh[2], bh[3]);

            if constexpr (SPLIT) {
                unsigned short al[4] = {
                    f32_to_bf16(av.x - bf16_to_f32(ah[0])),
                    f32_to_bf16(av.y - bf16_to_f32(ah[1])),
                    f32_to_bf16(av.z - bf16_to_f32(ah[2])),
                    f32_to_bf16(av.w - bf16_to_f32(ah[3]))};
                unsigned short bl[4] = {
                    f32_to_bf16(wvv.x - bf16_to_f32(bh[0])),
                    f32_to_bf16(wvv.y - bf16_to_f32(bh[1])),
                    f32_to_bf16(wvv.z - bf16_to_f32(bh[2])),
                    f32_to_bf16(wvv.w - bf16_to_f32(bh[3]))};
                *(ushort4*)&Alo[row * 32 + uoff] = make_ushort4(al[0], al[1], al[2], al[3]);
                *(ushort4*)&Blo[row * 32 + uoff] = make_ushort4(bl[0], bl[1], bl[2], bl[3]);
            }
        }
        __syncthreads();

        const int lrow = lane & 15;
        const int unit = lane >> 4;

        short8 bh_f[4], bl_f[4];
        #pragma unroll
        for (int fc = 0; fc < 4; ++fc) {
            bh_f[fc] = *(const short8*)&Bhi[frag_off(wc + fc * 16 + lrow, unit)];
            if constexpr (SPLIT)
                bl_f[fc] = *(const short8*)&Blo[frag_off(wc + fc * 16 + lrow, unit)];
        }
        #pragma unroll
        for (int fr = 0; fr < 4; ++fr) {
            const short8 ah_f = *(const short8*)&Ahi[frag_off(wr + fr * 16 + lrow, unit)];
            if constexpr (SPLIT) {
                const short8 al_f = *(const short8*)&Alo[frag_off(wr + fr * 16 + lrow, unit)];
                #pragma unroll
                for (int fc = 0; fc < 4; ++fc) {
                    acc[fr][fc] = __builtin_amdgcn_mfma_f32_16x16x32_bf16(ah_f, bh_f[fc], acc[fr][fc], 0, 0, 0);
                    acc[fr][fc] = __builtin_amdgcn_mfma_f32_16x16x32_bf16(ah_f, bl_f[fc], acc[fr][fc], 0, 0, 0);
                    acc[fr][fc] = __builtin_amdgcn_mfma_f32_16x16x32_bf16(al_f, bh_f[fc], acc[fr][fc], 0, 0, 0);
                }
            } else {
                #pragma unroll
                for (int fc = 0; fc < 4; ++fc)
                    acc[fr][fc] = __builtin_amdgcn_mfma_f32_16x16x32_bf16(ah_f, bh_f[fc], acc[fr][fc], 0, 0, 0);
            }
        }
    }

    const int ccol = lane & 15;
    const int crow = (lane >> 4) * 4;
    #pragma unroll
    for (int fr = 0; fr < 4; ++fr) {
        #pragma unroll
        for (int fc = 0; fc < 4; ++fc) {
            const int col = col0 + wc + fc * 16 + ccol;
            float bias = 0.f;
            if constexpr (NB >= 1) bias += b1[col];
            if constexpr (NB >= 2) bias += b2[col];
            #pragma unroll
            for (int j = 0; j < 4; ++j) {
                const int row = row0 + wr + fr * 16 + crow + j;
                float v = acc[fr][fc][j] + bias;
                if constexpr (ACT == 1) v = tanhf(v);
                else if constexpr (ACT == 2) v = 1.0f / (1.0f + expf(-v));
                outp[(size_t)row * N + col] = v;
            }
        }
    }
}

// ============ persistent recurrence: all 512 steps, one launch ============
// v2: (a) Wh fragments hoisted into registers BEFORE the t-loop (16 short8 =
// 64 VGPR/thread — loop-invariant, removes all W VMEM from steady state);
// (b) flag-array barrier: leader stores flag[bid]=t+1 (sc0 sc1) after per-wave
// vmcnt(0) drain + __syncthreads; wave 0's 32 lanes poll the group's 32
// contiguous flags with coalesced sc0 sc1 loads (no RMW serialization).
// h state: packed (bf16hi|bf16lo) u32 planes via sc0 sc1 (coherence point,
// bypasses non-coherent per-XCD L2s). Numerics identical to step_v4.
__global__ __launch_bounds__(512, 1)
void rnn_persistent(const unsigned int* __restrict__ Ppk,  // [2][B][H] packed
                    const unsigned short* __restrict__ Whi,
                    const unsigned short* __restrict__ Wlo,
                    float* __restrict__ all_h,
                    unsigned int* __restrict__ flags)      // [256]
{
    __shared__ float red[8][16][33];

    const int tid  = threadIdx.x;
    const int bid  = blockIdx.x;
    const int y    = bid >> 5;          // row-group 0..7
    const int x    = bid & 31;          // col-block 0..31 (XCD = x%8)
    const int r0   = y * 16;
    const int c0   = x * 32;

    const int w    = tid >> 6;          // wave: k-range [w*128, +128)
    const int lane = tid & 63;
    const int lr   = lane & 15;
    const int kg   = lane >> 4;

    const int ep_r = tid >> 5, ep_c = tid & 31;
    const size_t ep_idx = (size_t)(r0 + ep_r) * H_ + (c0 + ep_c);

    // ---- hoist Wh fragments: constant across all 512 steps ----
    const int kbase = w * 128 + kg * 8;
    const unsigned short* pb0h = Whi + (size_t)(c0 + lr) * H_ + kbase;
    const unsigned short* pb0l = Wlo + (size_t)(c0 + lr) * H_ + kbase;
    const unsigned short* pb1h = Whi + (size_t)(c0 + 16 + lr) * H_ + kbase;
    const unsigned short* pb1l = Wlo + (size_t)(c0 + 16 + lr) * H_ + kbase;

    short8 wb0h[4], wb0l[4], wb1h[4], wb1l[4];
    #pragma unroll
    for (int it = 0; it < 4; ++it) {
        const int ko = it * 32;
        wb0h[it] = *(const short8*)(pb0h + ko);
        wb0l[it] = *(const short8*)(pb0l + ko);
        wb1h[it] = *(const short8*)(pb1h + ko);
        wb1l[it] = *(const short8*)(pb1l + ko);
    }

    for (int t = 0; t < T_; ++t) {
        float* __restrict__ hdst = all_h + (size_t)(t + 1) * BH;
        const float xpv = hdst[ep_idx];          // staged xp (overlaps A-loads)

        // ---- packed h_t, 8x dwordx4 sc0 sc1 ----
        const unsigned int* abase = Ppk + (size_t)(t & 1) * BH
                                  + (size_t)(r0 + lr) * H_ + kbase;
        uint4 c0v, c1v, c2v, c3v, c4v, c5v, c6v, c7v;
        asm volatile(
            "global_load_dwordx4 %0, %8, off sc0 sc1\n\t"
            "global_load_dwordx4 %1, %8, off offset:16 sc0 sc1\n\t"
            "global_load_dwordx4 %2, %8, off offset:128 sc0 sc1\n\t"
            "global_load_dwordx4 %3, %8, off offset:144 sc0 sc1\n\t"
            "global_load_dwordx4 %4, %8, off offset:256 sc0 sc1\n\t"
            "global_load_dwordx4 %5, %8, off offset:272 sc0 sc1\n\t"
            "global_load_dwordx4 %6, %8, off offset:384 sc0 sc1\n\t"
            "global_load_dwordx4 %7, %8, off offset:400 sc0 sc1\n\t"
            "s_waitcnt vmcnt(0)"
            : "=&v"(c0v), "=&v"(c1v), "=&v"(c2v), "=&v"(c3v),
              "=&v"(c4v), "=&v"(c5v), "=&v"(c6v), "=&v"(c7v)
            : "v"(abase)
            : "memory");

        f32x4 acc0 = {0.f, 0.f, 0.f, 0.f}, acc1 = {0.f, 0.f, 0.f, 0.f};
        const uint4 chunks[8] = {c0v, c1v, c2v, c3v, c4v, c5v, c6v, c7v};

        #pragma unroll
        for (int it = 0; it < 4; ++it) {
            short8 ah, al;
            #pragma unroll
            for (int j = 0; j < 4; ++j) {
                const unsigned int u0 = ((const unsigned int*)&chunks[2 * it])[j];
                const unsigned int u1 = ((const unsigned int*)&chunks[2 * it + 1])[j];
                ah[j]     = (short)(u0 & 0xffffu);
                al[j]     = (short)(u0 >> 16);
                ah[4 + j] = (short)(u1 & 0xffffu);
                al[4 + j] = (short)(u1 >> 16);
            }
            acc0 = __builtin_amdgcn_mfma_f32_16x16x32_bf16(ah, wb0h[it], acc0, 0, 0, 0);
            acc0 = __builtin_amdgcn_mfma_f32_16x16x32_bf16(ah, wb0l[it], acc0, 0, 0, 0);
            acc0 = __builtin_amdgcn_mfma_f32_16x16x32_bf16(al, wb0h[it], acc0, 0, 0, 0);
            acc0 = __builtin_amdgcn_mfma_f32_16x16x32_bf16(al, wb0l[it], acc0, 0, 0, 0);
            acc1 = __builtin_amdgcn_mfma_f32_16x16x32_bf16(ah, wb1h[it], acc1, 0, 0, 0);
            acc1 = __builtin_amdgcn_mfma_f32_16x16x32_bf16(ah, wb1l[it], acc1, 0, 0, 0);
            acc1 = __builtin_amdgcn_mfma_f32_16x16x32_bf16(al, wb1h[it], acc1, 0, 0, 0);
            acc1 = __builtin_amdgcn_mfma_f32_16x16x32_bf16(al, wb1l[it], acc1, 0, 0, 0);
        }

        #pragma unroll
        for (int j = 0; j < 4; ++j) {
            red[w][kg * 4 + j][lr]      = acc0[j];
            red[w][kg * 4 + j][16 + lr] = acc1[j];
        }
        __syncthreads();

        // epilogue: one cell/thread
        {
            float s = ((red[0][ep_r][ep_c] + red[1][ep_r][ep_c])
                     + (red[2][ep_r][ep_c] + red[3][ep_r][ep_c]))
                    + ((red[4][ep_r][ep_c] + red[5][ep_r][ep_c])
                     + (red[6][ep_r][ep_c] + red[7][ep_r][ep_c]));
            const float v = tanhf(s + xpv);
            hdst[ep_idx] = v;                    // plain store (output only)
            const unsigned short hi = f32_to_bf16(v);
            const unsigned short lo = f32_to_bf16(v - bf16_to_f32(hi));
            const unsigned int pk = (unsigned int)hi | ((unsigned int)lo << 16);
            const unsigned int* qp = Ppk + (size_t)((t + 1) & 1) * BH + ep_idx;
            asm volatile("global_store_dword %0, %1, off sc0 sc1"
                         :: "v"(qp), "v"(pk) : "memory");
        }

        // ---- intra-group barrier: flag array, no RMWs ----
        asm volatile("s_waitcnt vmcnt(0)" ::: "memory");   // per-wave drain
        __syncthreads();                                   // all waves drained
        if (tid == 0) {
            const unsigned int* fp = flags + bid;
            const unsigned int val = (unsigned int)(t + 1);
            asm volatile("global_store_dword %0, %1, off sc0 sc1\n\t"
                         "s_waitcnt vmcnt(0)"
                         :: "v"(fp), "v"(val) : "memory");
        }
        if (w == 0) {
            const unsigned int want = (unsigned int)(t + 1);
            const unsigned int* fp = flags + y * 32 + (lane & 31);
            unsigned int v = 0;
            int spins = 0;
            do {
                asm volatile("global_load_dword %0, %1, off sc0 sc1\n\t"
                             "s_waitcnt vmcnt(0)"
                             : "=v"(v) : "v"(fp) : "memory");
                if (v >= want) break_hint: ;
                if (++spins > (1 << 17)) break;            // fail-fast, never hang
                if (v < want) __builtin_amdgcn_s_sleep(2);
            } while (!__all(v >= want));
        }
        __syncthreads();
    }
}

// ---------------- step_v4 fallback (round 8) ----------------
__global__ __launch_bounds__(512)
void step_v4(const unsigned short* __restrict__ Phi, const unsigned short* __restrict__ Plo,
             const unsigned short* __restrict__ Whi, const unsigned short* __restrict__ Wlo,
             float* __restrict__ hdst,
             unsigned short* __restrict__ Qhi, unsigned short* __restrict__ Qlo)
{
    __shared__ float red[8][16][33];

    const int tid  = threadIdx.x;
    const int c0   = blockIdx.x * 32;
    const int r0   = blockIdx.y * 16;
    const int w    = tid >> 6;
    const int lane = tid & 63;
    const int lr   = lane & 15;
    const int kg   = lane >> 4;

    const int ep_r = tid >> 5, ep_c = tid & 31;
    const size_t ep_idx = (size_t)(r0 + ep_r) * H_ + (c0 + ep_c);
    const float xpv = hdst[ep_idx];

    const int kbase = w * 128 + kg * 8;
    const unsigned short* pah = Phi + (size_t)(r0 + lr) * H_ + kbase;
    const unsigned short* pal = Plo + (size_t)(r0 + lr) * H_ + kbase;
    const unsigned short* pb0h = Whi + (size_t)(c0 + lr) * H_ + kbase;
    const unsigned short* pb0l = Wlo + (size_t)(c0 + lr) * H_ + kbase;
    const unsigned short* pb1h = Whi + (size_t)(c0 + 16 + lr) * H_ + kbase;
    const unsigned short* pb1l = Wlo + (size_t)(c0 + 16 + lr) * H_ + kbase;

    f32x4 acc0 = {0.f, 0.f, 0.f, 0.f}, acc1 = {0.f, 0.f, 0.f, 0.f};

    #pragma unroll
    for (int it = 0; it < 4; ++it) {
        const int ko = it * 32;
        const short8 ah  = *(const short8*)(pah + ko);
        const short8 al  = *(const short8*)(pal + ko);
        const short8 b0h = *(const short8*)(pb0h + ko);
        const short8 b0l = *(const short8*)(pb0l + ko);
        const short8 b1h = *(const short8*)(pb1h + ko);
        const short8 b1l = *(const short8*)(pb1l + ko);

        acc0 = __builtin_amdgcn_mfma_f32_16x16x32_bf16(ah, b0h, acc0, 0, 0, 0);
        acc0 = __builtin_amdgcn_mfma_f32_16x16x32_bf16(ah, b0l, acc0, 0, 0, 0);
        acc0 = __builtin_amdgcn_mfma_f32_16x16x32_bf16(al, b0h, acc0, 0, 0, 0);
        acc0 = __builtin_amdgcn_mfma_f32_16x16x32_bf16(al, b0l, acc0, 0, 0, 0);
        acc1 = __builtin_amdgcn_mfma_f32_16x16x32_bf16(ah, b1h, acc1, 0, 0, 0);
        acc1 = __builtin_amdgcn_mfma_f32_16x16x32_bf16(ah, b1l, acc1, 0, 0, 0);
        acc1 = __builtin_amdgcn_mfma_f32_16x16x32_bf16(al, b1h, acc1, 0, 0, 0);
        acc1 = __builtin_amdgcn_mfma_f32_16x16x32_bf16(al, b1l, acc1, 0, 0, 0);
    }

    #pragma unroll
    for (int j = 0; j < 4; ++j) {
        red[w][kg * 4 + j][lr]      = acc0[j];
        red[w][kg * 4 + j][16 + lr] = acc1[j];
    }
    __syncthreads();

    float s = ((red[0][ep_r][ep_c] + red[1][ep_r][ep_c])
             + (red[2][ep_r][ep_c] + red[3][ep_r][ep_c]))
            + ((red[4][ep_r][ep_c] + red[5][ep_r][ep_c])
             + (red[6][ep_r][ep_c] + red[7][ep_r][ep_c]));
    const float v = tanhf(s + xpv);
    hdst[ep_idx] = v;
    const unsigned short hi = f32_to_bf16(v);
    Qhi[ep_idx] = hi;
    Qlo[ep_idx] = f32_to_bf16(v - bf16_to_f32(hi));
}

// ---------------- step_v3 fallback (round 6) ----------------
__global__ __launch_bounds__(512)
void step_v3(const float* __restrict__ hsrc, const float* __restrict__ Wh,
             float* __restrict__ hdst)
{
    __shared__ float hS[16][1024];
    __shared__ float red[16][33];

    const int tid = threadIdx.x;
    const int c0  = blockIdx.x * 32;
    const int r0  = blockIdx.y * 16;

    const int ep_r = tid >> 5, ep_c = tid & 31;
    const size_t ep_idx = (size_t)(r0 + ep_r) * H_ + (c0 + ep_c);
    const float xpv = hdst[ep_idx];

    #pragma unroll
    for (int it = 0; it < 8; ++it) {
        const int chunk = tid + it * 512;
        const int row = chunk >> 8;
        const int k4  = (chunk & 255) * 4;
        *(float4*)&hS[row][k4] =
            *(const float4*)(hsrc + (size_t)(r0 + row) * H_ + k4);
    }
    __syncthreads();

    const int w     = tid >> 6;
    const int lane  = tid & 63;
    const int kslot = lane & 15;
    const int rq    = lane >> 4;

    float acc[4][4];
    #pragma unroll
    for (int r = 0; r < 4; ++r)
        #pragma unroll
        for (int c = 0; c < 4; ++c) acc[r][c] = 0.f;

    const float* whb = Wh + (size_t)(c0 + w * 4) * H_ + kslot * 4;

    #pragma unroll 4
    for (int i = 0; i < 16; ++i) {
        const int k = kslot * 4 + i * 64;
        float4 hv[4];
        #pragma unroll
        for (int r = 0; r < 4; ++r)
            hv[r] = *(const float4*)&hS[rq * 4 + r][k];
        #pragma unroll
        for (int c = 0; c < 4; ++c) {
            const float4 wvv = *(const float4*)(whb + (size_t)c * H_ + i * 64);
            #pragma unroll
            for (int r = 0; r < 4; ++r) {
                acc[r][c] = fmaf(hv[r].x, wvv.x, acc[r][c]);
                acc[r][c] = fmaf(hv[r].y, wvv.y, acc[r][c]);
                acc[r][c] = fmaf(hv[r].z, wvv.z, acc[r][c]);
                acc[r][c] = fmaf(hv[r].w, wvv.w, acc[r][c]);
            }
        }
    }

    #pragma unroll
    for (int m = 1; m < 16; m <<= 1)
        #pragma unroll
        for (int r = 0; r < 4; ++r)
            #pragma unroll
            for (int c = 0; c < 4; ++c)
                acc[r][c] += __shfl_xor(acc[r][c], m, 64);

    if (kslot == 0) {
        #pragma unroll
        for (int r = 0; r < 4; ++r)
            #pragma unroll
            for (int c = 0; c < 4; ++c)
                red[rq * 4 + r][w * 4 + c] = acc[r][c];
    }
    __syncthreads();

    hdst[ep_idx] = tanhf(red[ep_r][ep_c] + xpv);
}

extern "C" void kernel_launch(void* const* d_in, const int* in_sizes, int n_in,
                              void* d_out, int out_size, void* d_ws, size_t ws_size,
                              hipStream_t stream)
{
    const float* x    = (const float*)d_in[0];
    const float* h0   = (const float*)d_in[1];
    const float* Wx_w = (const float*)d_in[2];
    const float* Wx_b = (const float*)d_in[3];
    const float* Wh_w = (const float*)d_in[4];
    const float* Wh_b = (const float*)d_in[5];
    const float* Wo_w = (const float*)d_in[6];
    const float* Wo_b = (const float*)d_in[7];

    float* out   = (float*)d_out;
    float* all_h = out;                              // [T+1][B][H]
    float* all_y = out + (size_t)(T_ + 1) * BH;      // [T][B][OUT]
    float* last  = all_y + (size_t)T_ * B_ * OUT_;   // [B][OUT]

    // all_h[0] = h0
    copy_h0_kernel<<<dim3((B_*H_ + 255)/256), dim3(256), 0, stream>>>(h0, all_h);

    // xproj = x@Wx^T + Wx_b + Wh_b (bf16x3 MFMA) -> staged into all_h[1..T]
    mfma_gemm<1, 2, 0><<<dim3(H_/128, (T_*B_)/128), dim3(256), 0, stream>>>(
        x, Wx_w, Wx_b, Wh_b, all_h + BH, T_*B_, H_, DIM_);

    // ---- recurrence ----
    const size_t need_pers = 2 * HH * sizeof(unsigned short)
                           + (2 * BH + 256) * sizeof(unsigned int);
    const size_t need_v4   = (2 * HH + 4 * BH) * sizeof(unsigned short);

    if (ws_size >= need_pers) {
        unsigned short* Whi = (unsigned short*)d_ws;
        unsigned short* Wlo = Whi + HH;
        unsigned int*   Ppk = (unsigned int*)(Whi + 2 * HH);   // [2][B][H]
        unsigned int*   flg = Ppk + 2 * BH;                    // [256]

        cvt_planes_kernel<<<dim3((int)(HH/4/256)), dim3(256), 0, stream>>>(
            Wh_w, Whi, Wlo, (int)(HH/4));
        pack_plane_kernel<<<dim3((int)(BH/256)), dim3(256), 0, stream>>>(
            h0, Ppk, (int)BH);
        hipMemsetAsync(flg, 0, 256 * sizeof(unsigned int), stream);

        rnn_persistent<<<dim3(256), dim3(512), 0, stream>>>(
            Ppk, Whi, Wlo, all_h, flg);
    } else if (ws_size >= need_v4) {
        unsigned short* wsu = (unsigned short*)d_ws;
        unsigned short* Whi = wsu;
        unsigned short* Wlo = wsu + HH;
        unsigned short* P0h = wsu + 2 * HH;
        unsigned short* P0l = P0h + BH;
        unsigned short* P1h = P0l + BH;
        unsigned short* P1l = P1h + BH;

        cvt_planes_kernel<<<dim3((int)(HH/4/256)), dim3(256), 0, stream>>>(
            Wh_w, Whi, Wlo, (int)(HH/4));
        cvt_planes_kernel<<<dim3((int)(BH/4/256)), dim3(256), 0, stream>>>(
            h0, P0h, P0l, (int)(BH/4));

        for (int t = 0; t < T_; ++t) {
            unsigned short* ph = (t & 1) ? P1h : P0h;
            unsigned short* pl = (t & 1) ? P1l : P0l;
            unsigned short* qh = (t & 1) ? P0h : P1h;
            unsigned short* ql = (t & 1) ? P0l : P1l;
            step_v4<<<dim3(32, 8), dim3(512), 0, stream>>>(
                ph, pl, Whi, Wlo, all_h + (size_t)(t + 1) * BH, qh, ql);
        }
    } else {
        for (int t = 0; t < T_; ++t) {
            step_v3<<<dim3(32, 8), dim3(512), 0, stream>>>(
                all_h + (size_t)t * BH, Wh_w, all_h + (size_t)(t + 1) * BH);
        }
    }

    // all_y = sigmoid(hs @ Wo^T + Wo_b)  (plain bf16 MFMA — downstream of scan)
    mfma_gemm<0, 1, 2><<<dim3(OUT_/128, (T_*B_)/128), dim3(256), 0, stream>>>(
        all_h + BH, Wo_w, Wo_b, nullptr, all_y, T_*B_, OUT_, H_);

    // last_logits = h_T @ Wo^T + Wo_b
    mfma_gemm<0, 1, 0><<<dim3(OUT_/128, 1), dim3(256), 0, stream>>>(
        all_h + (size_t)T_ * BH, Wo_w, Wo_b, nullptr, last, B_, OUT_, H_);
}

// Round 12
// 2791.632 us; speedup vs baseline: 1.7727x; 1.1228x over previous
//
#include <hip/hip_runtime.h>
#include <hip/hip_bf16.h>

static constexpr int T_ = 512, B_ = 128, DIM_ = 512, H_ = 1024, OUT_ = 512;
static constexpr size_t BH = (size_t)B_ * H_;
static constexpr size_t HH = (size_t)H_ * H_;
static constexpr unsigned int SENT = 0xFFFFFFFFu;   // packed bf16 NaN|NaN — unreachable

using short8 = __attribute__((ext_vector_type(8))) short;
using f32x4  = __attribute__((ext_vector_type(4))) float;

// ---- bf16 bit helpers (round-to-nearest-even) ----
__device__ __forceinline__ unsigned short f32_to_bf16(float x) {
    unsigned int u = __float_as_uint(x);
    u += 0x7fffu + ((u >> 16) & 1u);
    return (unsigned short)(u >> 16);
}
__device__ __forceinline__ float bf16_to_f32(unsigned short h) {
    return __uint_as_float(((unsigned int)h) << 16);
}

__global__ void copy_h0_kernel(const float* __restrict__ h0, float* __restrict__ out) {
    int i = blockIdx.x * blockDim.x + threadIdx.x;
    if (i < B_ * H_) out[i] = h0[i];
}

// f32 -> separate bf16 hi/lo planes (Wh, and v4 fallback state)
__global__ void cvt_planes_kernel(const float* __restrict__ src,
                                  unsigned short* __restrict__ hi,
                                  unsigned short* __restrict__ lo, int n4)
{
    int i = blockIdx.x * blockDim.x + threadIdx.x;
    if (i >= n4) return;
    const float4 v = *(const float4*)(src + (size_t)i * 4);
    unsigned short h[4] = {f32_to_bf16(v.x), f32_to_bf16(v.y),
                           f32_to_bf16(v.z), f32_to_bf16(v.w)};
    unsigned short l[4] = {f32_to_bf16(v.x - bf16_to_f32(h[0])),
                           f32_to_bf16(v.y - bf16_to_f32(h[1])),
                           f32_to_bf16(v.z - bf16_to_f32(h[2])),
                           f32_to_bf16(v.w - bf16_to_f32(h[3]))};
    *(ushort4*)(hi + (size_t)i * 4) = make_ushort4(h[0], h[1], h[2], h[3]);
    *(ushort4*)(lo + (size_t)i * 4) = make_ushort4(l[0], l[1], l[2], l[3]);
}

// f32 -> packed (hi | lo<<16) u32 plane
__global__ void pack_plane_kernel(const float* __restrict__ src,
                                  unsigned int* __restrict__ q, int n)
{
    int i = blockIdx.x * blockDim.x + threadIdx.x;
    if (i >= n) return;
    const float v = src[i];
    const unsigned short hi = f32_to_bf16(v);
    const unsigned short lo = f32_to_bf16(v - bf16_to_f32(hi));
    q[i] = (unsigned int)hi | ((unsigned int)lo << 16);
}

// ================= MFMA GEMM (unchanged from round 7) =================
template<int SPLIT, int NB, int ACT>
__launch_bounds__(256)
__global__ void mfma_gemm(const float* __restrict__ A, const float* __restrict__ W,
                          const float* __restrict__ b1, const float* __restrict__ b2,
                          float* __restrict__ outp, int M, int N, int K)
{
    __shared__ unsigned short Ahi[128 * 32], Alo[SPLIT ? 128 * 32 : 1];
    __shared__ unsigned short Bhi[128 * 32], Blo[SPLIT ? 128 * 32 : 1];

    const int tid  = threadIdx.x;
    const int col0 = blockIdx.x * 128;
    const int row0 = blockIdx.y * 128;

    const int wv   = tid >> 6;
    const int lane = tid & 63;
    const int wr   = (wv >> 1) * 64;
    const int wc   = (wv & 1) * 64;

    f32x4 acc[4][4];
    #pragma unroll
    for (int i = 0; i < 4; ++i)
        #pragma unroll
        for (int j = 0; j < 4; ++j) acc[i][j] = (f32x4){0.f, 0.f, 0.f, 0.f};

    auto frag_off = [](int row, int unit) -> int {
        return row * 32 + ((unit ^ ((row >> 1) & 3)) << 3);
    };

    for (int k0 = 0; k0 < K; k0 += 32) {
        __syncthreads();
        #pragma unroll
        for (int i = 0; i < 4; ++i) {
            const int fid = tid + i * 256;
            const int row = fid >> 3;
            const int f4  = fid & 7;
            const int unit = f4 >> 1;
            const int uoff = ((unit ^ ((row >> 1) & 3)) << 3) + (f4 & 1) * 4;

            float4 av = *(const float4*)(A + (size_t)(row0 + row) * K + k0 + f4 * 4);
            float4 wvv = *(const float4*)(W + (size_t)(col0 + row) * K + k0 + f4 * 4);

            unsigned short ah[4] = {f32_to_bf16(av.x), f32_to_bf16(av.y),
                                    f32_to_bf16(av.z), f32_to_bf16(av.w)};
            unsigned short bh[4] = {f32_to_bf16(wvv.x), f32_to_bf16(wvv.y),
                                    f32_to_bf16(wvv.z), f32_to_bf16(wvv.w)};
            *(ushort4*)&Ahi[row * 32 + uoff] = make_ushort4(ah[0], ah[1], ah[2], ah[3]);
            *(ushort4*)&Bhi[row * 32 + uoff] = make_ushort4(bh[0], bh[1], bh[2], bh[3]);

            if constexpr (SPLIT) {
                unsigned short al[4] = {
                    f32_to_bf16(av.x - bf16_to_f32(ah[0])),
                    f32_to_bf16(av.y - bf16_to_f32(ah[1])),
                    f32_to_bf16(av.z - bf16_to_f32(ah[2])),
                    f32_to_bf16(av.w - bf16_to_f32(ah[3]))};
                unsigned short bl[4] = {
                    f32_to_bf16(wvv.x - bf16_to_f32(bh[0])),
                    f32_to_bf16(wvv.y - bf16_to_f32(bh[1])),
                    f32_to_bf16(wvv.z - bf16_to_f32(bh[2])),
                    f32_to_bf16(wvv.w - bf16_to_f32(bh[3]))};
                *(ushort4*)&Alo[row * 32 + uoff] = make_ushort4(al[0], al[1], al[2], al[3]);
                *(ushort4*)&Blo[row * 32 + uoff] = make_ushort4(bl[0], bl[1], bl[2], bl[3]);
            }
        }
        __syncthreads();

        const int lrow = lane & 15;
        const int unit = lane >> 4;

        short8 bh_f[4], bl_f[4];
        #pragma unroll
        for (int fc = 0; fc < 4; ++fc) {
            bh_f[fc] = *(const short8*)&Bhi[frag_off(wc + fc * 16 + lrow, unit)];
            if constexpr (SPLIT)
                bl_f[fc] = *(const short8*)&Blo[frag_off(wc + fc * 16 + lrow, unit)];
        }
        #pragma unroll
        for (int fr = 0; fr < 4; ++fr) {
            const short8 ah_f = *(const short8*)&Ahi[frag_off(wr + fr * 16 + lrow, unit)];
            if constexpr (SPLIT) {
                const short8 al_f = *(const short8*)&Alo[frag_off(wr + fr * 16 + lrow, unit)];
                #pragma unroll
                for (int fc = 0; fc < 4; ++fc) {
                    acc[fr][fc] = __builtin_amdgcn_mfma_f32_16x16x32_bf16(ah_f, bh_f[fc], acc[fr][fc], 0, 0, 0);
                    acc[fr][fc] = __builtin_amdgcn_mfma_f32_16x16x32_bf16(ah_f, bl_f[fc], acc[fr][fc], 0, 0, 0);
                    acc[fr][fc] = __builtin_amdgcn_mfma_f32_16x16x32_bf16(al_f, bh_f[fc], acc[fr][fc], 0, 0, 0);
                }
            } else {
                #pragma unroll
                for (int fc = 0; fc < 4; ++fc)
                    acc[fr][fc] = __builtin_amdgcn_mfma_f32_16x16x32_bf16(ah_f, bh_f[fc], acc[fr][fc], 0, 0, 0);
            }
        }
    }

    const int ccol = lane & 15;
    const int crow = (lane >> 4) * 4;
    #pragma unroll
    for (int fr = 0; fr < 4; ++fr) {
        #pragma unroll
        for (int fc = 0; fc < 4; ++fc) {
            const int col = col0 + wc + fc * 16 + ccol;
            float bias = 0.f;
            if constexpr (NB >= 1) bias += b1[col];
            if constexpr (NB >= 2) bias += b2[col];
            #pragma unroll
            for (int j = 0; j < 4; ++j) {
                const int row = row0 + wr + fr * 16 + crow + j;
                float v = acc[fr][fc][j] + bias;
                if constexpr (ACT == 1) v = tanhf(v);
                else if constexpr (ACT == 2) v = 1.0f / (1.0f + expf(-v));
                outp[(size_t)row * N + col] = v;
            }
        }
    }
}

// ============ persistent recurrence v4: sentinel protocol ============
// Round-10 geometry + L3 (sc0 sc1) exchange — PROVEN correct. The data is its
// own flag: h state in 3 rotating packed-u32 buffers; readers poll their own
// fragment loads until no word == SENT. Owner clears its cells of buffer
// (t+2)%3 right after its poll succeeds (poll proves all step-(t-1) readers
// done), and drains (vmcnt 0) before storing h_{t+1} — L3 single serialization
// point then guarantees: whoever sees h_{t+1} also sees the clear. Removes the
// flag-store + flag-poll round trips. Numerics identical (same k-order).
__global__ __launch_bounds__(512, 1)
void rnn_persistent(unsigned int* __restrict__ Ppk,        // [3][B][H] packed
                    const unsigned short* __restrict__ Whi,
                    const unsigned short* __restrict__ Wlo,
                    float* __restrict__ all_h)
{
    __shared__ float red[8][16][33];

    const int tid  = threadIdx.x;
    const int bid  = blockIdx.x;
    const int y    = bid >> 5;          // row-group 0..7
    const int x    = bid & 31;          // col-block 0..31
    const int r0   = y * 16;
    const int c0   = x * 32;

    const int w    = tid >> 6;          // wave: k-range [w*128, +128)
    const int lane = tid & 63;
    const int lr   = lane & 15;
    const int kg   = lane >> 4;

    const int ep_r = tid >> 5, ep_c = tid & 31;
    const size_t ep_idx = (size_t)(r0 + ep_r) * H_ + (c0 + ep_c);

    // ---- hoist Wh fragments (loop-invariant; no memory clobbers below) ----
    const int kbase = w * 128 + kg * 8;
    short8 wb0h[4], wb0l[4], wb1h[4], wb1l[4];
    #pragma unroll
    for (int it = 0; it < 4; ++it) {
        const int ko = it * 32;
        wb0h[it] = *(const short8*)(Whi + (size_t)(c0 + lr) * H_ + kbase + ko);
        wb0l[it] = *(const short8*)(Wlo + (size_t)(c0 + lr) * H_ + kbase + ko);
        wb1h[it] = *(const short8*)(Whi + (size_t)(c0 + 16 + lr) * H_ + kbase + ko);
        wb1l[it] = *(const short8*)(Wlo + (size_t)(c0 + 16 + lr) * H_ + kbase + ko);
    }

    const size_t arow = (size_t)(r0 + lr) * H_ + kbase;

    for (int t = 0; t < T_; ++t) {
        float* __restrict__ hdst = all_h + (size_t)(t + 1) * BH;
        const float xpv = hdst[ep_idx];          // staged xp

        // ---- poll-load packed h_t from buffer t%3 until no SENT word ----
        const unsigned int* abase = Ppk + (size_t)(t % 3) * BH + arow;
        uint4 c0v, c1v, c2v, c3v, c4v, c5v, c6v, c7v;
        int spins = 0;
        bool ok;
        do {
            asm volatile(
                "global_load_dwordx4 %0, %8, off sc0 sc1\n\t"
                "global_load_dwordx4 %1, %8, off offset:16 sc0 sc1\n\t"
                "global_load_dwordx4 %2, %8, off offset:128 sc0 sc1\n\t"
                "global_load_dwordx4 %3, %8, off offset:144 sc0 sc1\n\t"
                "global_load_dwordx4 %4, %8, off offset:256 sc0 sc1\n\t"
                "global_load_dwordx4 %5, %8, off offset:272 sc0 sc1\n\t"
                "global_load_dwordx4 %6, %8, off offset:384 sc0 sc1\n\t"
                "global_load_dwordx4 %7, %8, off offset:400 sc0 sc1\n\t"
                "s_waitcnt vmcnt(0)"
                : "=&v"(c0v), "=&v"(c1v), "=&v"(c2v), "=&v"(c3v),
                  "=&v"(c4v), "=&v"(c5v), "=&v"(c6v), "=&v"(c7v)
                : "v"(abase));
            ok = true;
            #define CHK(u) ok &= ((u).x != SENT) & ((u).y != SENT) & \
                                 ((u).z != SENT) & ((u).w != SENT)
            CHK(c0v); CHK(c1v); CHK(c2v); CHK(c3v);
            CHK(c4v); CHK(c5v); CHK(c6v); CHK(c7v);
            #undef CHK
            if (__all(ok)) break;
            if (++spins > (1 << 17)) break;      // fail-wrong-fast, never hang
            __builtin_amdgcn_s_sleep(1);
        } while (true);

        // ---- clear own cell of buffer (t+2)%3 (holds consumed h_{t-1}) ----
        {
            unsigned int* cp = Ppk + (size_t)((t + 2) % 3) * BH + ep_idx;
            const unsigned int sv = SENT;
            asm volatile("global_store_dword %0, %1, off sc0 sc1"
                         :: "v"(cp), "v"(sv));
        }

        f32x4 acc0 = {0.f, 0.f, 0.f, 0.f}, acc1 = {0.f, 0.f, 0.f, 0.f};
        const uint4 chunks[8] = {c0v, c1v, c2v, c3v, c4v, c5v, c6v, c7v};

        #pragma unroll
        for (int it = 0; it < 4; ++it) {
            short8 ah, al;
            #pragma unroll
            for (int j = 0; j < 4; ++j) {
                const unsigned int u0 = ((const unsigned int*)&chunks[2 * it])[j];
                const unsigned int u1 = ((const unsigned int*)&chunks[2 * it + 1])[j];
                ah[j]     = (short)(u0 & 0xffffu);
                al[j]     = (short)(u0 >> 16);
                ah[4 + j] = (short)(u1 & 0xffffu);
                al[4 + j] = (short)(u1 >> 16);
            }
            acc0 = __builtin_amdgcn_mfma_f32_16x16x32_bf16(ah, wb0h[it], acc0, 0, 0, 0);
            acc0 = __builtin_amdgcn_mfma_f32_16x16x32_bf16(ah, wb0l[it], acc0, 0, 0, 0);
            acc0 = __builtin_amdgcn_mfma_f32_16x16x32_bf16(al, wb0h[it], acc0, 0, 0, 0);
            acc0 = __builtin_amdgcn_mfma_f32_16x16x32_bf16(al, wb0l[it], acc0, 0, 0, 0);
            acc1 = __builtin_amdgcn_mfma_f32_16x16x32_bf16(ah, wb1h[it], acc1, 0, 0, 0);
            acc1 = __builtin_amdgcn_mfma_f32_16x16x32_bf16(ah, wb1l[it], acc1, 0, 0, 0);
            acc1 = __builtin_amdgcn_mfma_f32_16x16x32_bf16(al, wb1h[it], acc1, 0, 0, 0);
            acc1 = __builtin_amdgcn_mfma_f32_16x16x32_bf16(al, wb1l[it], acc1, 0, 0, 0);
        }

        #pragma unroll
        for (int j = 0; j < 4; ++j) {
            red[w][kg * 4 + j][lr]      = acc0[j];
            red[w][kg * 4 + j][16 + lr] = acc1[j];
        }
        __syncthreads();

        // epilogue: one cell/thread; clear must be drained before pk store
        {
            float s = ((red[0][ep_r][ep_c] + red[1][ep_r][ep_c])
                     + (red[2][ep_r][ep_c] + red[3][ep_r][ep_c]))
                    + ((red[4][ep_r][ep_c] + red[5][ep_r][ep_c])
                     + (red[6][ep_r][ep_c] + red[7][ep_r][ep_c]));
            const float v = tanhf(s + xpv);
            hdst[ep_idx] = v;                    // plain store (output only)
            const unsigned short hi = f32_to_bf16(v);
            const unsigned short lo = f32_to_bf16(v - bf16_to_f32(hi));
            const unsigned int pk = (unsigned int)hi | ((unsigned int)lo << 16);
            unsigned int* qp = Ppk + (size_t)((t + 1) % 3) * BH + ep_idx;
            asm volatile("s_waitcnt vmcnt(0)\n\t"              // clear drained
                         "global_store_dword %0, %1, off sc0 sc1"
                         :: "v"(qp), "v"(pk));
        }
        __syncthreads();
    }
}

// ---------------- step_v4 fallback (round 8) ----------------
__global__ __launch_bounds__(512)
void step_v4(const unsigned short* __restrict__ Phi, const unsigned short* __restrict__ Plo,
             const unsigned short* __restrict__ Whi, const unsigned short* __restrict__ Wlo,
             float* __restrict__ hdst,
             unsigned short* __restrict__ Qhi, unsigned short* __restrict__ Qlo)
{
    __shared__ float red[8][16][33];

    const int tid  = threadIdx.x;
    const int c0   = blockIdx.x * 32;
    const int r0   = blockIdx.y * 16;
    const int w    = tid >> 6;
    const int lane = tid & 63;
    const int lr   = lane & 15;
    const int kg   = lane >> 4;

    const int ep_r = tid >> 5, ep_c = tid & 31;
    const size_t ep_idx = (size_t)(r0 + ep_r) * H_ + (c0 + ep_c);
    const float xpv = hdst[ep_idx];

    const int kbase = w * 128 + kg * 8;
    const unsigned short* pah = Phi + (size_t)(r0 + lr) * H_ + kbase;
    const unsigned short* pal = Plo + (size_t)(r0 + lr) * H_ + kbase;
    const unsigned short* pb0h = Whi + (size_t)(c0 + lr) * H_ + kbase;
    const unsigned short* pb0l = Wlo + (size_t)(c0 + lr) * H_ + kbase;
    const unsigned short* pb1h = Whi + (size_t)(c0 + 16 + lr) * H_ + kbase;
    const unsigned short* pb1l = Wlo + (size_t)(c0 + 16 + lr) * H_ + kbase;

    f32x4 acc0 = {0.f, 0.f, 0.f, 0.f}, acc1 = {0.f, 0.f, 0.f, 0.f};

    #pragma unroll
    for (int it = 0; it < 4; ++it) {
        const int ko = it * 32;
        const short8 ah  = *(const short8*)(pah + ko);
        const short8 al  = *(const short8*)(pal + ko);
        const short8 b0h = *(const short8*)(pb0h + ko);
        const short8 b0l = *(const short8*)(pb0l + ko);
        const short8 b1h = *(const short8*)(pb1h + ko);
        const short8 b1l = *(const short8*)(pb1l + ko);

        acc0 = __builtin_amdgcn_mfma_f32_16x16x32_bf16(ah, b0h, acc0, 0, 0, 0);
        acc0 = __builtin_amdgcn_mfma_f32_16x16x32_bf16(ah, b0l, acc0, 0, 0, 0);
        acc0 = __builtin_amdgcn_mfma_f32_16x16x32_bf16(al, b0h, acc0, 0, 0, 0);
        acc0 = __builtin_amdgcn_mfma_f32_16x16x32_bf16(al, b0l, acc0, 0, 0, 0);
        acc1 = __builtin_amdgcn_mfma_f32_16x16x32_bf16(ah, b1h, acc1, 0, 0, 0);
        acc1 = __builtin_amdgcn_mfma_f32_16x16x32_bf16(ah, b1l, acc1, 0, 0, 0);
        acc1 = __builtin_amdgcn_mfma_f32_16x16x32_bf16(al, b1h, acc1, 0, 0, 0);
        acc1 = __builtin_amdgcn_mfma_f32_16x16x32_bf16(al, b1l, acc1, 0, 0, 0);
    }

    #pragma unroll
    for (int j = 0; j < 4; ++j) {
        red[w][kg * 4 + j][lr]      = acc0[j];
        red[w][kg * 4 + j][16 + lr] = acc1[j];
    }
    __syncthreads();

    float s = ((red[0][ep_r][ep_c] + red[1][ep_r][ep_c])
             + (red[2][ep_r][ep_c] + red[3][ep_r][ep_c]))
            + ((red[4][ep_r][ep_c] + red[5][ep_r][ep_c])
             + (red[6][ep_r][ep_c] + red[7][ep_r][ep_c]));
    const float v = tanhf(s + xpv);
    hdst[ep_idx] = v;
    const unsigned short hi = f32_to_bf16(v);
    Qhi[ep_idx] = hi;
    Qlo[ep_idx] = f32_to_bf16(v - bf16_to_f32(hi));
}

extern "C" void kernel_launch(void* const* d_in, const int* in_sizes, int n_in,
                              void* d_out, int out_size, void* d_ws, size_t ws_size,
                              hipStream_t stream)
{
    const float* x    = (const float*)d_in[0];
    const float* h0   = (const float*)d_in[1];
    const float* Wx_w = (const float*)d_in[2];
    const float* Wx_b = (const float*)d_in[3];
    const float* Wh_w = (const float*)d_in[4];
    const float* Wh_b = (const float*)d_in[5];
    const float* Wo_w = (const float*)d_in[6];
    const float* Wo_b = (const float*)d_in[7];

    float* out   = (float*)d_out;
    float* all_h = out;                              // [T+1][B][H]
    float* all_y = out + (size_t)(T_ + 1) * BH;      // [T][B][OUT]
    float* last  = all_y + (size_t)T_ * B_ * OUT_;   // [B][OUT]

    // all_h[0] = h0
    copy_h0_kernel<<<dim3((B_*H_ + 255)/256), dim3(256), 0, stream>>>(h0, all_h);

    // xproj = x@Wx^T + Wx_b + Wh_b (bf16x3 MFMA) -> staged into all_h[1..T]
    mfma_gemm<1, 2, 0><<<dim3(H_/128, (T_*B_)/128), dim3(256), 0, stream>>>(
        x, Wx_w, Wx_b, Wh_b, all_h + BH, T_*B_, H_, DIM_);

    // ---- recurrence ----
    const size_t need_pers = 2 * HH * sizeof(unsigned short)
                           + 3 * BH * sizeof(unsigned int);
    const size_t need_v4   = (2 * HH + 4 * BH) * sizeof(unsigned short);

    if (ws_size >= need_pers) {
        unsigned short* Whi = (unsigned short*)d_ws;
        unsigned short* Wlo = Whi + HH;
        unsigned int*   Ppk = (unsigned int*)(Whi + 2 * HH);   // [3][B][H]

        cvt_planes_kernel<<<dim3((int)(HH/4/256)), dim3(256), 0, stream>>>(
            Wh_w, Whi, Wlo, (int)(HH/4));
        pack_plane_kernel<<<dim3((int)(BH/256)), dim3(256), 0, stream>>>(
            h0, Ppk, (int)BH);
        // buffers 1 and 2 pre-cleared to sentinel (0xFF bytes)
        hipMemsetAsync(Ppk + BH, 0xFF, 2 * BH * sizeof(unsigned int), stream);

        rnn_persistent<<<dim3(256), dim3(512), 0, stream>>>(
            Ppk, Whi, Wlo, all_h);
    } else if (ws_size >= need_v4) {
        unsigned short* wsu = (unsigned short*)d_ws;
        unsigned short* Whi = wsu;
        unsigned short* Wlo = wsu + HH;
        unsigned short* P0h = wsu + 2 * HH;
        unsigned short* P0l = P0h + BH;
        unsigned short* P1h = P0l + BH;
        unsigned short* P1l = P1h + BH;

        cvt_planes_kernel<<<dim3((int)(HH/4/256)), dim3(256), 0, stream>>>(
            Wh_w, Whi, Wlo, (int)(HH/4));
        cvt_planes_kernel<<<dim3((int)(BH/4/256)), dim3(256), 0, stream>>>(
            h0, P0h, P0l, (int)(BH/4));

        for (int t = 0; t < T_; ++t) {
            unsigned short* ph = (t & 1) ? P1h : P0h;
            unsigned short* pl = (t & 1) ? P1l : P0l;
            unsigned short* qh = (t & 1) ? P0h : P1h;
            unsigned short* ql = (t & 1) ? P0l : P1l;
            step_v4<<<dim3(32, 8), dim3(512), 0, stream>>>(
                ph, pl, Whi, Wlo, all_h + (size_t)(t + 1) * BH, qh, ql);
        }
    }

    // all_y = sigmoid(hs @ Wo^T + Wo_b)  (plain bf16 MFMA — downstream of scan)
    mfma_gemm<0, 1, 2><<<dim3(OUT_/128, (T_*B_)/128), dim3(256), 0, stream>>>(
        all_h + BH, Wo_w, Wo_b, nullptr, all_y, T_*B_, OUT_, H_);

    // last_logits = h_T @ Wo^T + Wo_b
    mfma_gemm<0, 1, 0><<<dim3(OUT_/128, 1), dim3(256), 0, stream>>>(
        all_h + (size_t)T_ * BH, Wo_w, Wo_b, nullptr, last, B_, OUT_, H_);
}